// Round 9
// baseline (147.174 us; speedup 1.0000x reference)
//
#include <hip/hip_runtime.h>
#include <math.h>

#define NN 1024
#define KK 256
#define NH 4
#define FD 64
#define HF 256
#define RL 68    // permuted prescaled row length (64 + pad to x4)
#define NG 17    // 4-float groups per row

typedef __attribute__((ext_vector_type(16))) float fx16;
typedef __attribute__((ext_vector_type(4)))  float fx4;

// ---- workspace float offsets (ws is ~268MB per fillBuffer evidence) ----
#define OFF_GR    0                      // g_r original [node][hf]      262144
#define OFF_GL2   262144                 // [node][head][RL] prescaled   278528
#define OFF_GR2   540672                 //                              278528
#define OFF_CL    819200                 // 4096
#define OFF_CR    823296                 // 4096
#define OFF_DENP  827392                 // 64 chunks x 4096 = 262144
#define OFF_P     1089536                // [h][j][i] 4M
#define OFF_ACCP  5283840                // 32 chunks x 262144
#define OFF_DEST  13672448               // 64 ints (perm dest)
#define OFF_ABSW  13672512               // 64 floats |w|
#define OFF_GPOS  13672576               // 1 int: npos4/4

// ---------------- prep: sign-partition permutation of the 64 features ----
__global__ void gatv2_prep(const float* __restrict__ aw, float* __restrict__ ws)
{
    const int f = threadIdx.x;                 // 64 threads = 1 wave
    const float wv = aw[f];
    const bool pos = (wv >= 0.f);
    const unsigned long long mask = __ballot(pos);
    const int npos  = __popcll(mask);
    const int npos4 = (npos + 3) & ~3;
    const unsigned long long lt = (1ull << f) - 1ull;
    const int prank = __popcll(mask & lt);
    const int nrank = __popcll(~mask & lt);
    const int dest  = pos ? prank : (npos4 + nrank);   // < 68 always
    ((int*)(ws + OFF_DEST))[f] = dest;
    (ws + OFF_ABSW)[f] = fabsf(wv);
    if (f == 0) ((int*)(ws + OFF_GPOS))[0] = npos4 >> 2;
}

// ---------------- GEMM + prescale/permute/cl/cr epilogue ----------------
__global__ __launch_bounds__(256) void gatv2_gemm(
    const float* __restrict__ hmat, const float* __restrict__ nei,
    const float* __restrict__ w_l, const float* __restrict__ w_r,
    const float* __restrict__ aw, float* __restrict__ ws)
{
    __shared__ float sA[16*260];
    const int t   = threadIdx.x;
    const int mb  = blockIdx.x;
    const int hd  = blockIdx.y;
    const int mat = blockIdx.z;
    const float* A = mat ? nei : hmat;
    const float* W = mat ? w_r : w_l;
    float* CC = ws + (mat ? OFF_CR : OFF_CL);

    #pragma unroll
    for (int rep = 0; rep < 4; ++rep) {
        const int flat = rep*256 + t;
        const int r = flat >> 6, c = (flat & 63) << 2;
        *(float4*)&sA[r*260 + c] = *(const float4*)&A[(size_t)(mb*16 + r)*KK + c];
    }
    __syncthreads();

    const int m  = t >> 4;
    const int nq = t & 15;
    const int ng = hd*64 + (nq << 2);
    const float* Wp = W + ng;

    float4 acc = make_float4(0.f, 0.f, 0.f, 0.f);
    #pragma unroll 4
    for (int k0 = 0; k0 < KK; k0 += 4) {
        const float4 a4 = *(const float4*)&sA[m*260 + k0];
        const float4 w0 = *(const float4*)(Wp + (size_t)(k0+0)*HF);
        const float4 w1 = *(const float4*)(Wp + (size_t)(k0+1)*HF);
        const float4 w2 = *(const float4*)(Wp + (size_t)(k0+2)*HF);
        const float4 w3 = *(const float4*)(Wp + (size_t)(k0+3)*HF);
        acc.x += a4.x*w0.x; acc.y += a4.x*w0.y; acc.z += a4.x*w0.z; acc.w += a4.x*w0.w;
        acc.x += a4.y*w1.x; acc.y += a4.y*w1.y; acc.z += a4.y*w1.z; acc.w += a4.y*w1.w;
        acc.x += a4.z*w2.x; acc.y += a4.z*w2.y; acc.z += a4.z*w2.z; acc.w += a4.z*w2.w;
        acc.x += a4.w*w3.x; acc.y += a4.w*w3.y; acc.z += a4.w*w3.z; acc.w += a4.w*w3.w;
    }

    const int node = mb*16 + m;
    if (mat) *(float4*)&(ws + OFF_GR)[(size_t)node*HF + ng] = acc;  // orig g_r (PV)

    // prescaled + sign-permuted scatter: g2[dest] = |w|*g
    {
        const int*   destp = (const int*)(ws + OFF_DEST);
        const int4   dv = ((const int4*)destp)[nq];
        const float4 av = ((const float4*)(ws + OFF_ABSW))[nq];
        float* g2 = ws + (mat ? OFF_GR2 : OFF_GL2) + ((size_t)node*NH + hd)*RL;
        g2[dv.x] = av.x*acc.x; g2[dv.y] = av.y*acc.y;
        g2[dv.z] = av.z*acc.z; g2[dv.w] = av.w*acc.w;
    }

    // cl/cr = 0.6 * sum_f w*g via xor-reduce
    {
        const float4 w4 = ((const float4*)aw)[nq];
        float wd = w4.x*acc.x + w4.y*acc.y + w4.z*acc.z + w4.w*acc.w;
        wd += __shfl_xor(wd, 1);
        wd += __shfl_xor(wd, 2);
        wd += __shfl_xor(wd, 4);
        wd += __shfl_xor(wd, 8);
        if (nq == 0) CC[hd*NN + node] = 0.6f*wd;
    }
}

// ---------------- e-phase: LDS row broadcast, Mi=2, no w array ----------
// e = cr + cl + sum_g m_g * sum4|gl2+gr2|, m_g = +-0.4 (sign-permuted rows).
// One ds_read_b128 broadcast feeds BOTH i's (Mi=2) -> ~1.6 LDS cyc/pair.
__global__ __launch_bounds__(256, 2) void gatv2_e(
    const float* __restrict__ wsro, const float* __restrict__ adj,
    float* __restrict__ P, float* __restrict__ denP)
{
    __shared__ float sgl[16*RL];
    __shared__ float scl[16];
    const float* gl2 = wsro + OFF_GL2;
    const float* gr2 = wsro + OFF_GR2;
    const float* cl  = wsro + OFF_CL;
    const float* cr  = wsro + OFF_CR;
    const int t  = threadIdx.x;
    const int jc = blockIdx.x;   // 64 chunks of 16 j
    const int ib = blockIdx.y;   // 2
    const int hh = blockIdx.z;   // 4
    const int i0 = ib*512 + t;
    const int i1 = i0 + 256;
    const int j0 = jc*16;

    // stage 16 gl2 rows + cl for the chunk
    for (int idx = t; idx < 16*NG; idx += 256) {
        const int r = idx / NG, c = idx - r*NG;
        *(float4*)&sgl[r*RL + (c<<2)] =
            *(const float4*)&gl2[((size_t)(j0+r)*NH + hh)*RL + (c<<2)];
    }
    if (t < 16) scl[t] = cl[hh*NN + j0 + t];

    // own rows, laundered element-wise (defeat remat; single-operand asms)
    fx4 ga[NG], gb[NG];
    {
        const fx4* pa = (const fx4*)(gr2 + ((size_t)i0*NH + hh)*RL);
        const fx4* pb = (const fx4*)(gr2 + ((size_t)i1*NH + hh)*RL);
        #pragma unroll
        for (int g = 0; g < NG; ++g) { ga[g] = pa[g]; gb[g] = pb[g]; }
    }
    #pragma unroll
    for (int g = 0; g < NG; ++g) { asm volatile("" : "+v"(ga[g])); }
    #pragma unroll
    for (int g = 0; g < NG; ++g) { asm volatile("" : "+v"(gb[g])); }

    const int gpos = ((const int*)(wsro + OFF_GPOS))[0];
    float mg[NG];
    #pragma unroll
    for (int g = 0; g < NG; ++g) mg[g] = (g < gpos) ? 0.4f : -0.4f;
    #pragma unroll
    for (int g = 0; g < NG; ++g) { asm volatile("" : "+v"(mg[g])); }

    const float cr0 = cr[hh*NN + i0];
    const float cr1 = cr[hh*NN + i1];

    float den0 = 0.f, den1 = 0.f;
    __syncthreads();

    #pragma unroll 2
    for (int jj = 0; jj < 16; ++jj) {
        const int j = j0 + jj;
        const float mk0 = adj[(size_t)j*NN + i0];
        const float mk1 = adj[(size_t)j*NN + i1];
        float a0 = 0.f, a1 = 0.f;
        #pragma unroll
        for (int g = 0; g < NG; ++g) {
            const fx4 b  = *(const fx4*)&sgl[jj*RL + (g<<2)];  // broadcast
            const fx4 va = b + ga[g];
            const fx4 vb = b + gb[g];
            const float sa = (fabsf(va[0]) + fabsf(va[1])) + (fabsf(va[2]) + fabsf(va[3]));
            const float sb = (fabsf(vb[0]) + fabsf(vb[1])) + (fabsf(vb[2]) + fabsf(vb[3]));
            a0 = fmaf(mg[g], sa, a0);
            a1 = fmaf(mg[g], sb, a1);
        }
        const float clj = scl[jj];
        const float p0 = (mk0 != 0.f) ? __expf(cr0 + clj + a0) : 0.f;
        const float p1 = (mk1 != 0.f) ? __expf(cr1 + clj + a1) : 0.f;
        den0 += p0; den1 += p1;
        const size_t pb = ((size_t)hh*NN + j)*NN;
        P[pb + i0] = p0;
        P[pb + i1] = p1;
    }
    denP[((size_t)jc*NH + hh)*NN + i0] = den0;
    denP[((size_t)jc*NH + hh)*NN + i1] = den1;
}

// ---------------- Phase B: accP[jc] = P-chunk @ g_r (R6 verbatim) -------
#define PVFMA(G0, G1, PP)                                           \
    { _Pragma("unroll") for (int q = 0; q < 4; ++q) {               \
        acc[q].x   += (PP)*G0[q*4+0]; acc[q].y   += (PP)*G0[q*4+1]; \
        acc[q].z   += (PP)*G0[q*4+2]; acc[q].w   += (PP)*G0[q*4+3]; \
        acc[4+q].x += (PP)*G1[q*4+0]; acc[4+q].y += (PP)*G1[q*4+1]; \
        acc[4+q].z += (PP)*G1[q*4+2]; acc[4+q].w += (PP)*G1[q*4+3]; } }

__global__ __launch_bounds__(256, 4) void gatv2_pv(
    const float* __restrict__ wsro, float* __restrict__ accP)
{
    __shared__ float sT[256*36];
    const float* g_r = wsro + OFF_GR;
    const float* P   = wsro + OFF_P;
    const int t  = threadIdx.x;
    const int jc = blockIdx.x;      // 32 j-chunks of 32
    const int ib = blockIdx.y;      // 4 i-blocks of 256
    const int fs = blockIdx.z;      // 8 f-segments of 32
    const int hh = fs >> 1;
    const int f0 = hh*64 + (fs & 1)*32;
    const int i  = ib*256 + t;

    float4 acc[8];
    #pragma unroll
    for (int q = 0; q < 8; ++q) acc[q] = make_float4(0.f,0.f,0.f,0.f);

    const int j0 = jc*32;
    const size_t pb0 = ((size_t)hh*NN)*NN + i;

    fx16 a0, a1, b0, b1;
    {
        const float* gp = g_r + (size_t)j0*HF + f0;
        asm volatile(
            "s_load_dwordx16 %0, %2, 0x0\n\t"
            "s_load_dwordx16 %1, %2, 0x40\n\t"
            "s_waitcnt lgkmcnt(0)"
            : "=s"(a0), "=s"(a1) : "s"(gp));
    }
    float pA = P[pb0 + (size_t)j0*NN];

    for (int jj = 0; jj < 32; jj += 2) {
        const int j = j0 + jj;
        {
            const float* gp = g_r + (size_t)(j+1)*HF + f0;
            asm volatile(
                "s_load_dwordx16 %0, %2, 0x0\n\t"
                "s_load_dwordx16 %1, %2, 0x40"
                : "=s"(b0), "=s"(b1) : "s"(gp));
        }
        const float pB = P[pb0 + (size_t)(j+1)*NN];
        PVFMA(a0, a1, pA)
        asm volatile("s_waitcnt lgkmcnt(0)");
        {
            const int j2 = (jj + 2 < 32) ? (j + 2) : j0;
            const float* gp = g_r + (size_t)j2*HF + f0;
            asm volatile(
                "s_load_dwordx16 %0, %2, 0x0\n\t"
                "s_load_dwordx16 %1, %2, 0x40"
                : "=s"(a0), "=s"(a1) : "s"(gp));
            pA = P[pb0 + (size_t)j2*NN];
        }
        PVFMA(b0, b1, pB)
        asm volatile("s_waitcnt lgkmcnt(0)");
    }

    #pragma unroll
    for (int q = 0; q < 4; ++q) {
        *(float4*)&sT[t*36 + q*4] = acc[q];
        *(float4*)&sT[t*36 + 16 + q*4] = acc[4+q];
    }
    __syncthreads();
    #pragma unroll
    for (int rep = 0; rep < 8; ++rep) {
        const int idx = rep*256 + t;
        const int il = idx >> 3, fq = idx & 7;
        const float4 v = *(const float4*)&sT[il*36 + fq*4];
        *(float4*)&accP[(size_t)jc*(NN*HF) + (size_t)(ib*256 + il)*HF + f0 + fq*4] = v;
    }
}

// ---------------- Final: sum partials, /den, elu ----------------
__global__ __launch_bounds__(256) void gatv2_fin(
    const float* __restrict__ accP, const float* __restrict__ denP,
    const int* __restrict__ use_elu, float* __restrict__ out)
{
    const int idx4 = blockIdx.x*256 + threadIdx.x;
    const int i  = idx4 >> 6;
    const int hh = (idx4 >> 4) & 3;
    float4 s = make_float4(0.f,0.f,0.f,0.f);
    for (int c = 0; c < 32; ++c) {
        const float4 v = *(const float4*)&accP[(size_t)c*(NN*HF) + (size_t)idx4*4];
        s.x += v.x; s.y += v.y; s.z += v.z; s.w += v.w;
    }
    float d = 0.f;
    for (int c = 0; c < 64; ++c) d += denP[((size_t)c*NH + hh)*NN + i];
    const float rd = 1.f / d;
    float4 r = make_float4(s.x*rd, s.y*rd, s.z*rd, s.w*rd);
    if (*use_elu != 0) {
        r.x = (r.x > 0.f) ? r.x : expm1f(r.x);
        r.y = (r.y > 0.f) ? r.y : expm1f(r.y);
        r.z = (r.z > 0.f) ? r.z : expm1f(r.z);
        r.w = (r.w > 0.f) ? r.w : expm1f(r.w);
    }
    ((float4*)out)[idx4] = r;
}

extern "C" void kernel_launch(void* const* d_in, const int* in_sizes, int n_in,
                              void* d_out, int out_size, void* d_ws, size_t ws_size,
                              hipStream_t stream)
{
    const float* hmat = (const float*)d_in[0];
    const float* nei  = (const float*)d_in[1];
    const float* adj  = (const float*)d_in[2];
    const float* w_l  = (const float*)d_in[3];
    const float* w_r  = (const float*)d_in[4];
    const float* aw   = (const float*)d_in[5];
    const int*   uel  = (const int*)d_in[6];
    float* out = (float*)d_out;
    float* ws  = (float*)d_ws;

    // zero gl2+gr2 (pad slots must be 0; ws re-poisoned 0xAA each launch)
    hipMemsetAsync((void*)(ws + OFF_GL2), 0, (size_t)2*278528*sizeof(float), stream);
    hipLaunchKernelGGL(gatv2_prep, dim3(1), dim3(64), 0, stream, aw, ws);
    hipLaunchKernelGGL(gatv2_gemm, dim3(64,4,2), dim3(256), 0, stream,
                       hmat, nei, w_l, w_r, aw, ws);
    hipLaunchKernelGGL(gatv2_e, dim3(64,2,4), dim3(256), 0, stream,
                       ws, adj, ws + OFF_P, ws + OFF_DENP);
    hipLaunchKernelGGL(gatv2_pv, dim3(32,4,8), dim3(256), 0, stream,
                       ws, ws + OFF_ACCP);
    hipLaunchKernelGGL(gatv2_fin, dim3((NN*HF)/1024), dim3(256), 0, stream,
                       ws + OFF_ACCP, ws + OFF_DENP, uel, out);
}

// Round 10
// 145.024 us; speedup vs baseline: 1.0148x; 1.0148x over previous
//
#include <hip/hip_runtime.h>
#include <math.h>

#define NN 1024
#define KK 256
#define NH 4
#define FD 64
#define HF 256
#define RL 68    // permuted prescaled row length (64 + pad to x4)
#define NG 17    // 4-float groups per row

typedef __attribute__((ext_vector_type(16))) float fx16;
typedef __attribute__((ext_vector_type(4)))  float fx4;

// ---- workspace float offsets ----
#define OFF_GR    0                      // g_r original [node][hf]
#define OFF_GL2   262144                 // [node][head][RL] prescaled+permuted
#define OFF_GR2   540672
#define OFF_CL    819200
#define OFF_CR    823296
#define OFF_DENP  827392                 // 64 chunks x 4096
#define OFF_P     1089536                // [h][j][i] 4M
#define OFF_ACCP  5283840                // 32 chunks x 262144
#define OFF_DEST  13672448               // 64 ints (perm dest)
#define OFF_ABSW  13672512               // 64 floats |w|
#define OFF_GPOS  13672576               // 1 int: npos4/4

// ---------------- prep: sign-partition permutation of the 64 features ----
__global__ void gatv2_prep(const float* __restrict__ aw, float* __restrict__ ws)
{
    const int f = threadIdx.x;                 // 64 threads = 1 wave
    const float wv = aw[f];
    const bool pos = (wv >= 0.f);
    const unsigned long long mask = __ballot(pos);
    const int npos  = __popcll(mask);
    const int npos4 = (npos + 3) & ~3;
    const unsigned long long lt = (1ull << f) - 1ull;
    const int prank = __popcll(mask & lt);
    const int nrank = __popcll(~mask & lt);
    const int dest  = pos ? prank : (npos4 + nrank);   // < 68 always
    ((int*)(ws + OFF_DEST))[f] = dest;
    (ws + OFF_ABSW)[f] = fabsf(wv);
    if (f == 0) ((int*)(ws + OFF_GPOS))[0] = npos4 >> 2;
}

// ---------------- GEMM + prescale/permute/cl/cr epilogue ----------------
__global__ __launch_bounds__(256) void gatv2_gemm(
    const float* __restrict__ hmat, const float* __restrict__ nei,
    const float* __restrict__ w_l, const float* __restrict__ w_r,
    const float* __restrict__ aw, float* __restrict__ ws)
{
    __shared__ float sA[16*260];
    const int t   = threadIdx.x;
    const int mb  = blockIdx.x;
    const int hd  = blockIdx.y;
    const int mat = blockIdx.z;
    const float* A = mat ? nei : hmat;
    const float* W = mat ? w_r : w_l;
    float* CC = ws + (mat ? OFF_CR : OFF_CL);

    #pragma unroll
    for (int rep = 0; rep < 4; ++rep) {
        const int flat = rep*256 + t;
        const int r = flat >> 6, c = (flat & 63) << 2;
        *(float4*)&sA[r*260 + c] = *(const float4*)&A[(size_t)(mb*16 + r)*KK + c];
    }
    __syncthreads();

    const int m  = t >> 4;
    const int nq = t & 15;
    const int ng = hd*64 + (nq << 2);
    const float* Wp = W + ng;

    float4 acc = make_float4(0.f, 0.f, 0.f, 0.f);
    #pragma unroll 4
    for (int k0 = 0; k0 < KK; k0 += 4) {
        const float4 a4 = *(const float4*)&sA[m*260 + k0];
        const float4 w0 = *(const float4*)(Wp + (size_t)(k0+0)*HF);
        const float4 w1 = *(const float4*)(Wp + (size_t)(k0+1)*HF);
        const float4 w2 = *(const float4*)(Wp + (size_t)(k0+2)*HF);
        const float4 w3 = *(const float4*)(Wp + (size_t)(k0+3)*HF);
        acc.x += a4.x*w0.x; acc.y += a4.x*w0.y; acc.z += a4.x*w0.z; acc.w += a4.x*w0.w;
        acc.x += a4.y*w1.x; acc.y += a4.y*w1.y; acc.z += a4.y*w1.z; acc.w += a4.y*w1.w;
        acc.x += a4.z*w2.x; acc.y += a4.z*w2.y; acc.z += a4.z*w2.z; acc.w += a4.z*w2.w;
        acc.x += a4.w*w3.x; acc.y += a4.w*w3.y; acc.z += a4.w*w3.z; acc.w += a4.w*w3.w;
    }

    const int node = mb*16 + m;
    if (mat) *(float4*)&(ws + OFF_GR)[(size_t)node*HF + ng] = acc;  // orig g_r (PV)

    // prescaled + sign-permuted scatter: g2[dest] = |w|*g
    {
        const int*   destp = (const int*)(ws + OFF_DEST);
        const int4   dv = ((const int4*)destp)[nq];
        const float4 av = ((const float4*)(ws + OFF_ABSW))[nq];
        float* g2 = ws + (mat ? OFF_GR2 : OFF_GL2) + ((size_t)node*NH + hd)*RL;
        g2[dv.x] = av.x*acc.x; g2[dv.y] = av.y*acc.y;
        g2[dv.z] = av.z*acc.z; g2[dv.w] = av.w*acc.w;
    }

    // cl/cr = 0.6 * sum_f w*g via xor-reduce
    {
        const float4 w4 = ((const float4*)aw)[nq];
        float wd = w4.x*acc.x + w4.y*acc.y + w4.z*acc.z + w4.w*acc.w;
        wd += __shfl_xor(wd, 1);
        wd += __shfl_xor(wd, 2);
        wd += __shfl_xor(wd, 4);
        wd += __shfl_xor(wd, 8);
        if (nq == 0) CC[hd*NN + node] = 0.6f*wd;
    }
}

// ---------------- e-phase: SGPR row stream + permuted prescaled rows ----
// Thread owns (i,h). Per j: gl2 row (68) -> SGPRs via s_load (scalar pipe,
// zero LDS/VMEM inner ops). e = cr + cl + sum_g mg_g * sum4|row_s + gri_v|,
// mg = +-0.4 (laundered VGPRs). Inner op pair: v_add(s,v) + abs-adds + fma.
// VGPR ~110 (3 waves/EU), SGPR ~90 (row 68 + ptrs): both budgets close.
#define EGRP(RS, QB, q)                                             \
    { const fx4 gq = g[(QB)+(q)];                                   \
      const float t0 = RS[(q)*4+0] + gq[0];                         \
      const float t1 = RS[(q)*4+1] + gq[1];                         \
      const float t2 = RS[(q)*4+2] + gq[2];                         \
      const float t3 = RS[(q)*4+3] + gq[3];                         \
      a = fmaf(mg[(QB)+(q)],                                        \
               (fabsf(t0)+fabsf(t1))+(fabsf(t2)+fabsf(t3)), a); }

#define EBLK4(RS, QB) EGRP(RS, QB, 0) EGRP(RS, QB, 1) EGRP(RS, QB, 2) EGRP(RS, QB, 3)

__global__ __launch_bounds__(256, 3) void gatv2_e(
    const float* __restrict__ wsro, const float* __restrict__ adj,
    float* __restrict__ P, float* __restrict__ denP)
{
    const float* gl2 = wsro + OFF_GL2;
    const float* gr2 = wsro + OFF_GR2;
    const float* cl  = wsro + OFF_CL;
    const float* cr  = wsro + OFF_CR;
    const int t  = threadIdx.x;
    const int jc = blockIdx.x;   // 64 chunks of 16 j
    const int ib = blockIdx.y;   // 4 i-blocks of 256
    const int hh = blockIdx.z;   // 4
    const int i  = ib*256 + t;
    const int j0 = jc*16;

    // own prescaled permuted row -> VGPRs, laundered element-wise vs remat
    fx4 g[NG];
    {
        const fx4* gp = (const fx4*)(gr2 + ((size_t)i*NH + hh)*RL);
        #pragma unroll
        for (int q = 0; q < NG; ++q) g[q] = gp[q];
    }
    #pragma unroll
    for (int q = 0; q < NG; ++q) { asm volatile("" : "+v"(g[q])); }

    // mg = +-0.4 per group (sign-permuted layout), laundered VGPRs
    const int gpos = ((const int*)(wsro + OFF_GPOS))[0];
    float mg[NG];
    #pragma unroll
    for (int q = 0; q < NG; ++q) mg[q] = (q < gpos) ? 0.4f : -0.4f;
    #pragma unroll
    for (int q = 0; q < NG; ++q) { asm volatile("" : "+v"(mg[q])); }

    const float cri = cr[hh*NN + i];

    float denl = 0.f;
    for (int jj = 0; jj < 16; ++jj) {
        const int j = j0 + jj;
        const float mask = adj[(size_t)j*NN + i];

        fx16 r0, r1, r2, r3; fx4 r4; float clv;
        {   // gl2 row (68 floats) + cl -> SGPRs; wait inside asm
            const float* rowp = gl2 + ((size_t)j*NH + hh)*RL;
            const float* clp  = cl + hh*NN + j;
            asm volatile(
                "s_load_dwordx16 %0, %6, 0x0\n\t"
                "s_load_dwordx16 %1, %6, 0x40\n\t"
                "s_load_dwordx16 %2, %6, 0x80\n\t"
                "s_load_dwordx16 %3, %6, 0xc0\n\t"
                "s_load_dwordx4  %4, %6, 0x100\n\t"
                "s_load_dword %5, %7, 0x0\n\t"
                "s_waitcnt lgkmcnt(0)"
                : "=s"(r0), "=s"(r1), "=s"(r2), "=s"(r3), "=s"(r4), "=s"(clv)
                : "s"(rowp), "s"(clp));
        }
        float a = 0.f;
        EBLK4(r0, 0) EBLK4(r1, 4) EBLK4(r2, 8) EBLK4(r3, 12)
        EGRP(r4, 16, 0)
        const float e  = cri + clv + a;
        const float pw = (mask != 0.f) ? __expf(e) : 0.f;
        denl += pw;
        P[((size_t)hh*NN + j)*NN + i] = pw;
    }
    denP[((size_t)jc*NH + hh)*NN + i] = denl;
}

// ---------------- Phase B: accP[jc] = P-chunk @ g_r ----------------
#define PVFMA(G0, G1, PP)                                           \
    { _Pragma("unroll") for (int q = 0; q < 4; ++q) {               \
        acc[q].x   += (PP)*G0[q*4+0]; acc[q].y   += (PP)*G0[q*4+1]; \
        acc[q].z   += (PP)*G0[q*4+2]; acc[q].w   += (PP)*G0[q*4+3]; \
        acc[4+q].x += (PP)*G1[q*4+0]; acc[4+q].y += (PP)*G1[q*4+1]; \
        acc[4+q].z += (PP)*G1[q*4+2]; acc[4+q].w += (PP)*G1[q*4+3]; } }

__global__ __launch_bounds__(256, 4) void gatv2_pv(
    const float* __restrict__ wsro, float* __restrict__ accP)
{
    __shared__ float sT[256*36];
    const float* g_r = wsro + OFF_GR;
    const float* P   = wsro + OFF_P;
    const int t  = threadIdx.x;
    const int jc = blockIdx.x;      // 32 j-chunks of 32
    const int ib = blockIdx.y;      // 4 i-blocks of 256
    const int fs = blockIdx.z;      // 8 f-segments of 32
    const int hh = fs >> 1;
    const int f0 = hh*64 + (fs & 1)*32;
    const int i  = ib*256 + t;

    float4 acc[8];
    #pragma unroll
    for (int q = 0; q < 8; ++q) acc[q] = make_float4(0.f,0.f,0.f,0.f);

    const int j0 = jc*32;
    const size_t pb0 = ((size_t)hh*NN)*NN + i;

    fx16 a0, a1, b0, b1;
    {
        const float* gp = g_r + (size_t)j0*HF + f0;
        asm volatile(
            "s_load_dwordx16 %0, %2, 0x0\n\t"
            "s_load_dwordx16 %1, %2, 0x40\n\t"
            "s_waitcnt lgkmcnt(0)"
            : "=s"(a0), "=s"(a1) : "s"(gp));
    }
    float pA = P[pb0 + (size_t)j0*NN];

    for (int jj = 0; jj < 32; jj += 2) {
        const int j = j0 + jj;
        {
            const float* gp = g_r + (size_t)(j+1)*HF + f0;
            asm volatile(
                "s_load_dwordx16 %0, %2, 0x0\n\t"
                "s_load_dwordx16 %1, %2, 0x40"
                : "=s"(b0), "=s"(b1) : "s"(gp));
        }
        const float pB = P[pb0 + (size_t)(j+1)*NN];
        PVFMA(a0, a1, pA)
        asm volatile("s_waitcnt lgkmcnt(0)");
        {
            const int j2 = (jj + 2 < 32) ? (j + 2) : j0;
            const float* gp = g_r + (size_t)j2*HF + f0;
            asm volatile(
                "s_load_dwordx16 %0, %2, 0x0\n\t"
                "s_load_dwordx16 %1, %2, 0x40"
                : "=s"(a0), "=s"(a1) : "s"(gp));
            pA = P[pb0 + (size_t)j2*NN];
        }
        PVFMA(b0, b1, pB)
        asm volatile("s_waitcnt lgkmcnt(0)");
    }

    #pragma unroll
    for (int q = 0; q < 4; ++q) {
        *(float4*)&sT[t*36 + q*4] = acc[q];
        *(float4*)&sT[t*36 + 16 + q*4] = acc[4+q];
    }
    __syncthreads();
    #pragma unroll
    for (int rep = 0; rep < 8; ++rep) {
        const int idx = rep*256 + t;
        const int il = idx >> 3, fq = idx & 7;
        const float4 v = *(const float4*)&sT[il*36 + fq*4];
        *(float4*)&accP[(size_t)jc*(NN*HF) + (size_t)(ib*256 + il)*HF + f0 + fq*4] = v;
    }
}

// ---------------- Final: sum partials, /den, elu ----------------
__global__ __launch_bounds__(256) void gatv2_fin(
    const float* __restrict__ accP, const float* __restrict__ denP,
    const int* __restrict__ use_elu, float* __restrict__ out)
{
    const int idx4 = blockIdx.x*256 + threadIdx.x;
    const int i  = idx4 >> 6;
    const int hh = (idx4 >> 4) & 3;
    float4 s = make_float4(0.f,0.f,0.f,0.f);
    for (int c = 0; c < 32; ++c) {
        const float4 v = *(const float4*)&accP[(size_t)c*(NN*HF) + (size_t)idx4*4];
        s.x += v.x; s.y += v.y; s.z += v.z; s.w += v.w;
    }
    float d = 0.f;
    for (int c = 0; c < 64; ++c) d += denP[((size_t)c*NH + hh)*NN + i];
    const float rd = 1.f / d;
    float4 r = make_float4(s.x*rd, s.y*rd, s.z*rd, s.w*rd);
    if (*use_elu != 0) {
        r.x = (r.x > 0.f) ? r.x : expm1f(r.x);
        r.y = (r.y > 0.f) ? r.y : expm1f(r.y);
        r.z = (r.z > 0.f) ? r.z : expm1f(r.z);
        r.w = (r.w > 0.f) ? r.w : expm1f(r.w);
    }
    ((float4*)out)[idx4] = r;
}

extern "C" void kernel_launch(void* const* d_in, const int* in_sizes, int n_in,
                              void* d_out, int out_size, void* d_ws, size_t ws_size,
                              hipStream_t stream)
{
    const float* hmat = (const float*)d_in[0];
    const float* nei  = (const float*)d_in[1];
    const float* adj  = (const float*)d_in[2];
    const float* w_l  = (const float*)d_in[3];
    const float* w_r  = (const float*)d_in[4];
    const float* aw   = (const float*)d_in[5];
    const int*   uel  = (const int*)d_in[6];
    float* out = (float*)d_out;
    float* ws  = (float*)d_ws;

    // zero gl2+gr2 (pad slots must be 0; ws re-poisoned 0xAA each launch)
    hipMemsetAsync((void*)(ws + OFF_GL2), 0, (size_t)2*278528*sizeof(float), stream);
    hipLaunchKernelGGL(gatv2_prep, dim3(1), dim3(64), 0, stream, aw, ws);
    hipLaunchKernelGGL(gatv2_gemm, dim3(64,4,2), dim3(256), 0, stream,
                       hmat, nei, w_l, w_r, aw, ws);
    hipLaunchKernelGGL(gatv2_e, dim3(64,4,4), dim3(256), 0, stream,
                       ws, adj, ws + OFF_P, ws + OFF_DENP);
    hipLaunchKernelGGL(gatv2_pv, dim3(32,4,8), dim3(256), 0, stream,
                       ws, ws + OFF_ACCP);
    hipLaunchKernelGGL(gatv2_fin, dim3((NN*HF)/1024), dim3(256), 0, stream,
                       ws + OFF_ACCP, ws + OFF_DENP, uel, out);
}